// Round 4
// baseline (1809.812 us; speedup 1.0000x reference)
//
#include <hip/hip_runtime.h>
#include <cstddef>
#include <cstdint>

#define N 1024
#define DN 128      // NODE_DIM
#define DE 16       // EDGE_DIM
#define DM 64       // MSG_DIM
#define TSTEPS 3
#define INDIM 272   // 2*DN + DE

// ---------------------------------------------------------------------------
// kInit: P[i,0:64]=hi, P[i,64:128]=hj, P[i,128:512]=gh+b_hh, from H=X.
// ---------------------------------------------------------------------------
__global__ __launch_bounds__(512, 4) void kInit(const float* __restrict__ H,
                                                const float* __restrict__ W1,
                                                const float* __restrict__ W_hh,
                                                const float* __restrict__ b_hh,
                                                float* __restrict__ P) {
  int i = blockIdx.x;
  int t = threadIdx.x;
  __shared__ float h[DN];
  if (t < DN) h[t] = H[(size_t)i * DN + t];
  __syncthreads();

  const float* w;
  float acc;
  if (t < 64)       { w = W1 + (size_t)t * INDIM;              acc = 0.f; }
  else if (t < 128) { w = W1 + (size_t)(t - 64) * INDIM + 128; acc = 0.f; }
  else              { w = W_hh + (size_t)(t - 128) * DN;       acc = b_hh[t - 128]; }
  const float4* w4 = (const float4*)w;
  float a0 = 0.f, a1 = 0.f;
  #pragma unroll
  for (int k4 = 0; k4 < DN / 8; ++k4) {
    float4 wv0 = w4[2 * k4];
    float4 wv1 = w4[2 * k4 + 1];
    a0 = fmaf(h[k4 * 8 + 0], wv0.x, a0);
    a1 = fmaf(h[k4 * 8 + 4], wv1.x, a1);
    a0 = fmaf(h[k4 * 8 + 1], wv0.y, a0);
    a1 = fmaf(h[k4 * 8 + 5], wv1.y, a1);
    a0 = fmaf(h[k4 * 8 + 2], wv0.z, a0);
    a1 = fmaf(h[k4 * 8 + 6], wv1.z, a1);
    a0 = fmaf(h[k4 * 8 + 3], wv0.w, a0);
    a1 = fmaf(h[k4 * 8 + 7], wv1.w, a1);
  }
  P[(size_t)i * 512 + t] = acc + a0 + a1;
}

// ---------------------------------------------------------------------------
// kStep: fused per-row step with A-compaction + LDS-staged E (T14 split).
// Block = row i, 256 threads (4 waves). lane = m (0..63), w = wave (0..3).
// ---------------------------------------------------------------------------
__global__ __launch_bounds__(256, 4) void kStep(const float* __restrict__ Pcur,
                                                const float* __restrict__ E,
                                                const float* __restrict__ W1,
                                                const float* __restrict__ b1,
                                                const int* __restrict__ A,
                                                const float* __restrict__ W2,
                                                const float* __restrict__ b2,
                                                const float* __restrict__ W_ih,
                                                const float* __restrict__ b_ih,
                                                const float* __restrict__ W_hh,
                                                const float* __restrict__ b_hh,
                                                const float* __restrict__ Hin,
                                                float* __restrict__ Hout,
                                                float* __restrict__ Pnext,
                                                int doPA) {
  int i    = blockIdx.x;
  int t    = threadIdx.x;
  int lane = t & 63;   // message dim m
  int w    = t >> 6;   // wave 0..3

  __shared__ int   sList[N];
  __shared__ float sE[2][64 * DE];   // double-buffered E tile: [slot][16]
  __shared__ int   sCnt[16];
  __shared__ int   sBase[16];
  __shared__ int   sDeg;
  __shared__ float red[4][DM];
  __shared__ float sS[DM];
  __shared__ float sM[DM];
  __shared__ float sGi[384];
  __shared__ float sH[DN];

  // ---- A-row compaction: list of active j's (order irrelevant) ----
  const int* Arow = A + (size_t)i * N;
  uint64_t lmask = (lane == 0) ? 0ull : ((~0ull) >> (64 - lane));
  int myj[4], mypre[4], myact[4];
  #pragma unroll
  for (int r = 0; r < 4; ++r) {
    int j = r * 256 + t;
    int a = Arow[j];
    uint64_t mask = __ballot(a != 0);
    myj[r]   = j;
    myact[r] = a;
    mypre[r] = __popcll(mask & lmask);
    if (lane == 0) sCnt[r * 4 + w] = __popcll(mask);
  }
  __syncthreads();
  if (t == 0) {
    int acc = 0;
    #pragma unroll
    for (int s = 0; s < 16; ++s) { sBase[s] = acc; acc += sCnt[s]; }
    sDeg = acc;
  }
  __syncthreads();
  #pragma unroll
  for (int r = 0; r < 4; ++r)
    if (myact[r]) sList[sBase[r * 4 + w] + mypre[r]] = myj[r];
  __syncthreads();
  int deg    = sDeg;
  int ntiles = (deg + 63) >> 6;
  int padded = ntiles << 6;
  if (t < padded - deg) sList[deg + t] = 0;   // pad slots get weight 0 below
  __syncthreads();

  // ---- We row (16 VGPRs) + hi + b1 ----
  float we[16];
  {
    const float4* wr4 = (const float4*)(W1 + (size_t)lane * INDIM + 256);
    #pragma unroll
    for (int q = 0; q < 4; ++q) {
      float4 v = wr4[q];
      we[q * 4 + 0] = v.x;
      we[q * 4 + 1] = v.y;
      we[q * 4 + 2] = v.z;
      we[q * 4 + 3] = v.w;
    }
  }
  float hib = Pcur[(size_t)i * 512 + lane] + b1[lane];

  // staging geometry: lane -> (slot within tile, 4-float chunk)
  int sl2 = (w << 4) + (lane >> 2);
  int ch4 = (lane & 3) * 4;
  const float* Ebase = E + (size_t)i * N * DE;

  // prologue: stage tile 0
  if (ntiles > 0) {
    int jv = sList[sl2];
    float4 ge = *(const float4*)(Ebase + (size_t)jv * DE + ch4);
    *(float4*)&sE[0][sl2 * DE + ch4] = ge;
  }
  __syncthreads();

  float s = 0.f;
  int buf = 0;
  for (int T = 0; T < ntiles; ++T) {
    int sb = (T << 6) + (w << 4);

    // hj loads for this tile (issued first: oldest in vmcnt order)
    float hj[16];
    #pragma unroll
    for (int k = 0; k < 16; ++k) {
      int jv = sList[sb + k];
      hj[k] = Pcur[(size_t)jv * 512 + 64 + lane];
    }

    // async-stage next tile's E into regs (younger than hj loads)
    float4 ge;
    bool doStage = (T + 1 < ntiles);
    if (doStage) {
      int jv2 = sList[((T + 1) << 6) + sl2];
      ge = *(const float4*)(Ebase + (size_t)jv2 * DE + ch4);
    }

    // compute this tile from LDS (wave-uniform broadcast reads)
    const float* eb = &sE[buf][(w << 4) * DE];
    #pragma unroll
    for (int k = 0; k < 16; ++k) {
      float acc = hib + hj[k];
      const float* ep = eb + k * DE;
      acc = fmaf(ep[0],  we[0],  acc);
      acc = fmaf(ep[1],  we[1],  acc);
      acc = fmaf(ep[2],  we[2],  acc);
      acc = fmaf(ep[3],  we[3],  acc);
      acc = fmaf(ep[4],  we[4],  acc);
      acc = fmaf(ep[5],  we[5],  acc);
      acc = fmaf(ep[6],  we[6],  acc);
      acc = fmaf(ep[7],  we[7],  acc);
      acc = fmaf(ep[8],  we[8],  acc);
      acc = fmaf(ep[9],  we[9],  acc);
      acc = fmaf(ep[10], we[10], acc);
      acc = fmaf(ep[11], we[11], acc);
      acc = fmaf(ep[12], we[12], acc);
      acc = fmaf(ep[13], we[13], acc);
      acc = fmaf(ep[14], we[14], acc);
      acc = fmaf(ep[15], we[15], acc);
      float wt = (sb + k < deg) ? 1.f : 0.f;
      s = fmaf(wt, fmaxf(acc, 0.f), s);
    }

    // write staged regs to the other buffer (latency covered by compute)
    if (doStage) *(float4*)&sE[buf ^ 1][sl2 * DE + ch4] = ge;
    __syncthreads();
    buf ^= 1;
  }

  // ---- S reduction across 4 waves ----
  red[w][lane] = s;
  __syncthreads();
  if (t < DM) {
    float acc = red[0][t] + red[1][t] + red[2][t] + red[3][t];
    sS[t] = acc;
  }
  __syncthreads();

  // ---- M = S @ W2.T + deg*b2 ----
  if (t < DM) {
    float acc = (float)deg * b2[t];
    const float4* w4 = (const float4*)(W2 + (size_t)t * DM);
    #pragma unroll
    for (int k4 = 0; k4 < DM / 4; ++k4) {
      float4 wv = w4[k4];
      acc = fmaf(sS[k4 * 4 + 0], wv.x, acc);
      acc = fmaf(sS[k4 * 4 + 1], wv.y, acc);
      acc = fmaf(sS[k4 * 4 + 2], wv.z, acc);
      acc = fmaf(sS[k4 * 4 + 3], wv.w, acc);
    }
    sM[t] = acc;
  }
  __syncthreads();

  // ---- gi = M @ W_ih.T + b_ih ----
  for (int c = t; c < 384; c += 256) {
    float acc = b_ih[c];
    const float4* w4 = (const float4*)(W_ih + (size_t)c * DM);
    #pragma unroll
    for (int k4 = 0; k4 < DM / 4; ++k4) {
      float4 wv = w4[k4];
      acc = fmaf(sM[k4 * 4 + 0], wv.x, acc);
      acc = fmaf(sM[k4 * 4 + 1], wv.y, acc);
      acc = fmaf(sM[k4 * 4 + 2], wv.z, acc);
      acc = fmaf(sM[k4 * 4 + 3], wv.w, acc);
    }
    sGi[c] = acc;
  }
  __syncthreads();

  // ---- GRU ----
  if (t < DN) {
    float ghr = Pcur[(size_t)i * 512 + 128 + t];
    float ghz = Pcur[(size_t)i * 512 + 256 + t];
    float ghn = Pcur[(size_t)i * 512 + 384 + t];
    float gir = sGi[t], giz = sGi[128 + t], gin = sGi[256 + t];
    float r = 1.f / (1.f + expf(-(gir + ghr)));
    float z = 1.f / (1.f + expf(-(giz + ghz)));
    float n = tanhf(gin + r * ghn);
    float h = Hin[(size_t)i * DN + t];
    float hn = (1.f - z) * n + z * h;
    sH[t] = hn;
    Hout[(size_t)i * DN + t] = hn;
  }
  __syncthreads();

  // ---- Pnext from new H row ----
  if (doPA) {
    for (int c = t; c < 512; c += 256) {
      const float* wp;
      float acc;
      if (c < 64)       { wp = W1 + (size_t)c * INDIM;              acc = 0.f; }
      else if (c < 128) { wp = W1 + (size_t)(c - 64) * INDIM + 128; acc = 0.f; }
      else              { wp = W_hh + (size_t)(c - 128) * DN;       acc = b_hh[c - 128]; }
      const float4* w4 = (const float4*)wp;
      float a0 = 0.f, a1 = 0.f;
      #pragma unroll
      for (int k4 = 0; k4 < DN / 8; ++k4) {
        float4 wv0 = w4[2 * k4];
        float4 wv1 = w4[2 * k4 + 1];
        a0 = fmaf(sH[k4 * 8 + 0], wv0.x, a0);
        a1 = fmaf(sH[k4 * 8 + 4], wv1.x, a1);
        a0 = fmaf(sH[k4 * 8 + 1], wv0.y, a0);
        a1 = fmaf(sH[k4 * 8 + 5], wv1.y, a1);
        a0 = fmaf(sH[k4 * 8 + 2], wv0.z, a0);
        a1 = fmaf(sH[k4 * 8 + 6], wv1.z, a1);
        a0 = fmaf(sH[k4 * 8 + 3], wv0.w, a0);
        a1 = fmaf(sH[k4 * 8 + 7], wv1.w, a1);
      }
      Pnext[(size_t)i * 512 + c] = acc + a0 + a1;
    }
  }
}

// ---------------------------------------------------------------------------
extern "C" void kernel_launch(void* const* d_in, const int* in_sizes, int n_in,
                              void* d_out, int out_size, void* d_ws, size_t ws_size,
                              hipStream_t stream) {
  const float* X    = (const float*)d_in[0];
  const int*   A    = (const int*)  d_in[1];
  const float* E    = (const float*)d_in[2];
  const float* W1   = (const float*)d_in[3];
  const float* b1   = (const float*)d_in[4];
  const float* W2   = (const float*)d_in[5];
  const float* b2   = (const float*)d_in[6];
  const float* W_ih = (const float*)d_in[7];
  const float* b_ih = (const float*)d_in[8];
  const float* W_hh = (const float*)d_in[9];
  const float* b_hh = (const float*)d_in[10];
  float* out = (float*)d_out;

  float* ws   = (float*)d_ws;
  float* Hbuf = ws;                 // N*DN   floats
  float* P0   = Hbuf + N * DN;      // N*512  floats
  float* P1   = P0 + N * 512;       // N*512  floats

  kInit<<<N, 512, 0, stream>>>(X, W1, W_hh, b_hh, P0);

  const float* Hin = X;
  float* Pc = P0;
  float* Pn = P1;
  for (int step = 0; step < TSTEPS; ++step) {
    int last = (step == TSTEPS - 1);
    float* Hout = last ? out : Hbuf;
    kStep<<<N, 256, 0, stream>>>(Pc, E, W1, b1, A, W2, b2, W_ih, b_ih,
                                 W_hh, b_hh, Hin, Hout, Pn, last ? 0 : 1);
    Hin = Hbuf;
    float* tmp = Pc; Pc = Pn; Pn = tmp;
  }
}

// Round 5
// 561.336 us; speedup vs baseline: 3.2241x; 3.2241x over previous
//
#include <hip/hip_runtime.h>
#include <cstddef>

#define N 1024
#define DN 128      // NODE_DIM
#define DE 16       // EDGE_DIM
#define DM 64       // MSG_DIM
#define TSTEPS 3
#define INDIM 272   // 2*DN + DE

// ---------------------------------------------------------------------------
// kA: P[i,c] for c in [0,512): c<64: hi[c] ; 64<=c<128: hj[c-64] ;
//     c>=128: gh[c-128]+b_hh.  Grid: (i, colHalf) = 2048 blocks, 256 thr.
// ---------------------------------------------------------------------------
__global__ __launch_bounds__(256, 8) void kA(const float* __restrict__ H,
                                             const float* __restrict__ W1,
                                             const float* __restrict__ W_hh,
                                             const float* __restrict__ b_hh,
                                             float* __restrict__ P) {
  int b = blockIdx.x;
  int i = b >> 1;
  int t = threadIdx.x;
  int c = ((b & 1) << 8) + t;

  __shared__ float h[DN];
  if (t < DN) h[t] = H[(size_t)i * DN + t];
  __syncthreads();

  const float* w;
  float bias = 0.f;
  if (c < 64)       { w = W1 + (size_t)c * INDIM; }
  else if (c < 128) { w = W1 + (size_t)(c - 64) * INDIM + 128; }
  else              { w = W_hh + (size_t)(c - 128) * DN; bias = b_hh[c - 128]; }
  const float4* w4 = (const float4*)w;

  float a0 = bias, a1 = 0.f;
  #pragma unroll
  for (int k = 0; k < 16; ++k) {
    float4 wv0 = w4[2 * k];
    float4 wv1 = w4[2 * k + 1];
    a0 = fmaf(h[8 * k + 0], wv0.x, a0);
    a1 = fmaf(h[8 * k + 4], wv1.x, a1);
    a0 = fmaf(h[8 * k + 1], wv0.y, a0);
    a1 = fmaf(h[8 * k + 5], wv1.y, a1);
    a0 = fmaf(h[8 * k + 2], wv0.z, a0);
    a1 = fmaf(h[8 * k + 6], wv1.z, a1);
    a0 = fmaf(h[8 * k + 3], wv0.w, a0);
    a1 = fmaf(h[8 * k + 7], wv1.w, a1);
  }
  P[(size_t)i * 512 + c] = a0 + a1;
}

// ---------------------------------------------------------------------------
// kB: block = (row i, j-partition p of 256 j's). 256 threads.
//   mh = t&31 -> m = {2mh, 2mh+1};  jj = t>>5 (8 j-lanes), 32 j's/thread.
//   S_part[(i*4+p)*64 + m] = sum over partition of A*relu(hi+hj+E@We+b1)
//   deg_part[i*4+p] = sum of A over partition.
// ---------------------------------------------------------------------------
__global__ __launch_bounds__(256, 5) void kB(const float* __restrict__ P,
                                             const float* __restrict__ E,
                                             const float* __restrict__ W1,
                                             const float* __restrict__ b1,
                                             const int* __restrict__ A,
                                             float* __restrict__ S_part,
                                             float* __restrict__ deg_part) {
  int b  = blockIdx.x;
  int i  = b >> 2;
  int p  = b & 3;
  int jbase = p << 8;
  int t  = threadIdx.x;
  int mh = t & 31;
  int jj = t >> 5;
  int m0 = mh << 1;

  __shared__ float sAf[256];
  __shared__ float red[8][DM];

  sAf[t] = (float)A[(size_t)i * N + jbase + t];

  // We rows for m0, m0+1 — 32 VGPRs, register-resident.
  float we0[16], we1[16];
  {
    const float4* wr0 = (const float4*)(W1 + (size_t)m0 * INDIM + 256);
    const float4* wr1 = (const float4*)(W1 + (size_t)(m0 + 1) * INDIM + 256);
    #pragma unroll
    for (int q = 0; q < 4; ++q) {
      float4 v0 = wr0[q];
      float4 v1 = wr1[q];
      we0[4 * q + 0] = v0.x; we1[4 * q + 0] = v1.x;
      we0[4 * q + 1] = v0.y; we1[4 * q + 1] = v1.y;
      we0[4 * q + 2] = v0.z; we1[4 * q + 2] = v1.z;
      we0[4 * q + 3] = v0.w; we1[4 * q + 3] = v1.w;
    }
  }
  float hib0 = P[(size_t)i * 512 + m0]     + b1[m0];
  float hib1 = P[(size_t)i * 512 + m0 + 1] + b1[m0 + 1];

  __syncthreads();

  float s0 = 0.f, s1 = 0.f;
  const float* Eb = E + ((size_t)i * N + jbase) * DE;

  for (int g = 0; g < 16; ++g) {   // 16 groups x 2 j's
    // ---- load both j's of this group first (explicit prefetch) ----
    float4 e0q0, e0q1, e0q2, e0q3, e1q0, e1q1, e1q2, e1q3;
    float2 hj0, hj1;
    float  a0, a1;
    int jl0 = (g << 4) + jj;       // g*16 + jj
    int jl1 = jl0 + 8;
    {
      const float4* e4 = (const float4*)(Eb + (size_t)jl0 * DE);
      e0q0 = e4[0]; e0q1 = e4[1]; e0q2 = e4[2]; e0q3 = e4[3];
    }
    {
      const float4* e4 = (const float4*)(Eb + (size_t)jl1 * DE);
      e1q0 = e4[0]; e1q1 = e4[1]; e1q2 = e4[2]; e1q3 = e4[3];
    }
    hj0 = *(const float2*)(P + (size_t)(jbase + jl0) * 512 + 64 + m0);
    hj1 = *(const float2*)(P + (size_t)(jbase + jl1) * 512 + 64 + m0);
    a0 = sAf[jl0];
    a1 = sAf[jl1];

    // ---- compute j0 ----
    {
      float c0 = hib0 + hj0.x;
      float c1 = hib1 + hj0.y;
      c0 = fmaf(e0q0.x, we0[0],  c0); c1 = fmaf(e0q0.x, we1[0],  c1);
      c0 = fmaf(e0q0.y, we0[1],  c0); c1 = fmaf(e0q0.y, we1[1],  c1);
      c0 = fmaf(e0q0.z, we0[2],  c0); c1 = fmaf(e0q0.z, we1[2],  c1);
      c0 = fmaf(e0q0.w, we0[3],  c0); c1 = fmaf(e0q0.w, we1[3],  c1);
      c0 = fmaf(e0q1.x, we0[4],  c0); c1 = fmaf(e0q1.x, we1[4],  c1);
      c0 = fmaf(e0q1.y, we0[5],  c0); c1 = fmaf(e0q1.y, we1[5],  c1);
      c0 = fmaf(e0q1.z, we0[6],  c0); c1 = fmaf(e0q1.z, we1[6],  c1);
      c0 = fmaf(e0q1.w, we0[7],  c0); c1 = fmaf(e0q1.w, we1[7],  c1);
      c0 = fmaf(e0q2.x, we0[8],  c0); c1 = fmaf(e0q2.x, we1[8],  c1);
      c0 = fmaf(e0q2.y, we0[9],  c0); c1 = fmaf(e0q2.y, we1[9],  c1);
      c0 = fmaf(e0q2.z, we0[10], c0); c1 = fmaf(e0q2.z, we1[10], c1);
      c0 = fmaf(e0q2.w, we0[11], c0); c1 = fmaf(e0q2.w, we1[11], c1);
      c0 = fmaf(e0q3.x, we0[12], c0); c1 = fmaf(e0q3.x, we1[12], c1);
      c0 = fmaf(e0q3.y, we0[13], c0); c1 = fmaf(e0q3.y, we1[13], c1);
      c0 = fmaf(e0q3.z, we0[14], c0); c1 = fmaf(e0q3.z, we1[14], c1);
      c0 = fmaf(e0q3.w, we0[15], c0); c1 = fmaf(e0q3.w, we1[15], c1);
      s0 = fmaf(a0, fmaxf(c0, 0.f), s0);
      s1 = fmaf(a0, fmaxf(c1, 0.f), s1);
    }
    // ---- compute j1 ----
    {
      float c0 = hib0 + hj1.x;
      float c1 = hib1 + hj1.y;
      c0 = fmaf(e1q0.x, we0[0],  c0); c1 = fmaf(e1q0.x, we1[0],  c1);
      c0 = fmaf(e1q0.y, we0[1],  c0); c1 = fmaf(e1q0.y, we1[1],  c1);
      c0 = fmaf(e1q0.z, we0[2],  c0); c1 = fmaf(e1q0.z, we1[2],  c1);
      c0 = fmaf(e1q0.w, we0[3],  c0); c1 = fmaf(e1q0.w, we1[3],  c1);
      c0 = fmaf(e1q1.x, we0[4],  c0); c1 = fmaf(e1q1.x, we1[4],  c1);
      c0 = fmaf(e1q1.y, we0[5],  c0); c1 = fmaf(e1q1.y, we1[5],  c1);
      c0 = fmaf(e1q1.z, we0[6],  c0); c1 = fmaf(e1q1.z, we1[6],  c1);
      c0 = fmaf(e1q1.w, we0[7],  c0); c1 = fmaf(e1q1.w, we1[7],  c1);
      c0 = fmaf(e1q2.x, we0[8],  c0); c1 = fmaf(e1q2.x, we1[8],  c1);
      c0 = fmaf(e1q2.y, we0[9],  c0); c1 = fmaf(e1q2.y, we1[9],  c1);
      c0 = fmaf(e1q2.z, we0[10], c0); c1 = fmaf(e1q2.z, we1[10], c1);
      c0 = fmaf(e1q2.w, we0[11], c0); c1 = fmaf(e1q2.w, we1[11], c1);
      c0 = fmaf(e1q3.x, we0[12], c0); c1 = fmaf(e1q3.x, we1[12], c1);
      c0 = fmaf(e1q3.y, we0[13], c0); c1 = fmaf(e1q3.y, we1[13], c1);
      c0 = fmaf(e1q3.z, we0[14], c0); c1 = fmaf(e1q3.z, we1[14], c1);
      c0 = fmaf(e1q3.w, we0[15], c0); c1 = fmaf(e1q3.w, we1[15], c1);
      s0 = fmaf(a1, fmaxf(c0, 0.f), s0);
      s1 = fmaf(a1, fmaxf(c1, 0.f), s1);
    }
  }

  *(float2*)&red[jj][m0] = make_float2(s0, s1);
  __syncthreads();

  if (t < DM) {
    float acc = red[0][t] + red[1][t] + red[2][t] + red[3][t]
              + red[4][t] + red[5][t] + red[6][t] + red[7][t];
    S_part[((size_t)(i << 2) + p) * DM + t] = acc;
  }
  if (t < 64) {
    float d = sAf[t] + sAf[t + 64] + sAf[t + 128] + sAf[t + 192];
    #pragma unroll
    for (int off = 32; off > 0; off >>= 1) d += __shfl_down(d, off);
    if (t == 0) deg_part[(i << 2) + p] = d;
  }
}

// ---------------------------------------------------------------------------
// kC: per row i: S = sum of 4 partials; M = S@W2.T + deg*b2;
//     gi = M@W_ih.T + b_ih; GRU with gh (P[i,128:512], b_hh included).
// ---------------------------------------------------------------------------
__global__ __launch_bounds__(256, 4) void kC(const float* __restrict__ P,
                                             const float* __restrict__ S_part,
                                             const float* __restrict__ deg_part,
                                             const float* __restrict__ W2,
                                             const float* __restrict__ b2,
                                             const float* __restrict__ W_ih,
                                             const float* __restrict__ b_ih,
                                             const float* __restrict__ Hin,
                                             float* __restrict__ Hout) {
  int i = blockIdx.x;
  int t = threadIdx.x;
  __shared__ float sS[DM];
  __shared__ float sM[DM];
  __shared__ float sGi[384];
  __shared__ float sdeg;

  if (t < DM) {
    const float* sp = S_part + ((size_t)i << 2) * DM + t;
    sS[t] = sp[0] + sp[DM] + sp[2 * DM] + sp[3 * DM];
  }
  if (t == 64) {
    const float* dp = deg_part + ((size_t)i << 2);
    sdeg = dp[0] + dp[1] + dp[2] + dp[3];
  }
  __syncthreads();

  if (t < DM) {
    float acc = sdeg * b2[t];
    const float4* w4 = (const float4*)(W2 + (size_t)t * DM);
    #pragma unroll
    for (int k4 = 0; k4 < DM / 4; ++k4) {
      float4 wv = w4[k4];
      acc = fmaf(sS[k4 * 4 + 0], wv.x, acc);
      acc = fmaf(sS[k4 * 4 + 1], wv.y, acc);
      acc = fmaf(sS[k4 * 4 + 2], wv.z, acc);
      acc = fmaf(sS[k4 * 4 + 3], wv.w, acc);
    }
    sM[t] = acc;
  }
  __syncthreads();

  for (int c = t; c < 384; c += 256) {
    float acc = b_ih[c];
    const float4* w4 = (const float4*)(W_ih + (size_t)c * DM);
    #pragma unroll
    for (int k4 = 0; k4 < DM / 4; ++k4) {
      float4 wv = w4[k4];
      acc = fmaf(sM[k4 * 4 + 0], wv.x, acc);
      acc = fmaf(sM[k4 * 4 + 1], wv.y, acc);
      acc = fmaf(sM[k4 * 4 + 2], wv.z, acc);
      acc = fmaf(sM[k4 * 4 + 3], wv.w, acc);
    }
    sGi[c] = acc;
  }
  __syncthreads();

  if (t < DN) {
    float ghr = P[(size_t)i * 512 + 128 + t];
    float ghz = P[(size_t)i * 512 + 256 + t];
    float ghn = P[(size_t)i * 512 + 384 + t];
    float gir = sGi[t], giz = sGi[128 + t], gin = sGi[256 + t];
    float r = 1.f / (1.f + expf(-(gir + ghr)));
    float z = 1.f / (1.f + expf(-(giz + ghz)));
    float n = tanhf(gin + r * ghn);
    float h = Hin[(size_t)i * DN + t];
    Hout[(size_t)i * DN + t] = (1.f - z) * n + z * h;
  }
}

// ---------------------------------------------------------------------------
extern "C" void kernel_launch(void* const* d_in, const int* in_sizes, int n_in,
                              void* d_out, int out_size, void* d_ws, size_t ws_size,
                              hipStream_t stream) {
  const float* X    = (const float*)d_in[0];
  const int*   A    = (const int*)  d_in[1];
  const float* E    = (const float*)d_in[2];
  const float* W1   = (const float*)d_in[3];
  const float* b1   = (const float*)d_in[4];
  const float* W2   = (const float*)d_in[5];
  const float* b2   = (const float*)d_in[6];
  const float* W_ih = (const float*)d_in[7];
  const float* b_ih = (const float*)d_in[8];
  const float* W_hh = (const float*)d_in[9];
  const float* b_hh = (const float*)d_in[10];
  float* out = (float*)d_out;

  float* ws       = (float*)d_ws;
  float* P        = ws;                       // N*512   = 524288 f
  float* S_part   = P + (size_t)N * 512;      // N*4*64  = 262144 f
  float* deg_part = S_part + (size_t)N * 4 * DM;  // 4096 f
  float* Hbuf     = deg_part + 4096;          // N*DN    = 131072 f

  const float* Hcur = X;
  for (int step = 0; step < TSTEPS; ++step) {
    int last = (step == TSTEPS - 1);
    kA<<<2048, 256, 0, stream>>>(Hcur, W1, W_hh, b_hh, P);
    kB<<<4096, 256, 0, stream>>>(P, E, W1, b1, A, S_part, deg_part);
    float* Hout = last ? out : Hbuf;
    kC<<<1024, 256, 0, stream>>>(P, S_part, deg_part, W2, b2, W_ih, b_ih,
                                 Hcur, Hout);
    Hcur = Hout;
  }
}